// Round 11
// baseline (104.743 us; speedup 1.0000x reference)
//
#include <hip/hip_runtime.h>
#include <math.h>

#define OUT_H 7
#define OUT_W 7
#define NBINS 49
#define REPS 3   // DIAGNOSTIC: 3 permuted passes in one dispatch so the kernel
                 // exceeds the ~43us top-5 profile cutoff and we finally get
                 // counters. Each rep processes a permuted roi set; every
                 // (n,c) output is written exactly REPS times with the same
                 // correct value -> result identical to 1 pass.

// R10 body + exact per-bin tall-row batches (mean loads 39 -> ~32).
// All memory ops statically unrolled with index clamping (dupes harmless
// under max). Bin bounds: exact integer floor(k*roi/7) == (k*roi)/7
// (absmax 0 since R4). Grid bx = n*64+cg, c = cg*4+wave.
__global__ __launch_bounds__(256) void roipool_v11(
    const float* __restrict__ feat, const int* __restrict__ rois,
    float* __restrict__ out)
{
    constexpr int C = 256, H = 64, W = 64;
    __shared__ float racc_lds[4][OUT_H][W + 1];

    const int bx   = blockIdx.x;
    const int n0   = bx >> 6;          // roi (128)
    const int cg   = bx & 63;
    const int tid  = threadIdx.x;
    const int lane = tid & 63;         // == x
    const int wave = tid >> 6;
    const int c    = cg * 4 + wave;

    const float* planes = feat + ((size_t)c) * (H * W);

    for (int rep = 0; rep < REPS; ++rep) {
        const int n = (n0 + rep * 37) & 127;   // roi permutation per rep

        const int* r = rois + n * 5;
        const int b  = r[0];
        const int x1 = r[1];
        const int y1 = r[2];
        const int roi_w = r[3] - x1 + 1;
        const int roi_h = r[4] - y1 + 1;

        const float* plane = planes + ((size_t)(b * C)) * (H * W);

        int hb[OUT_H + 1];
#pragma unroll
        for (int k = 0; k <= OUT_H; ++k) hb[k] = (k * roi_h) / OUT_H;

        float racc[OUT_H];
        {
            float v[OUT_H][4];
#pragma unroll
            for (int ph = 0; ph < OUT_H; ++ph) {
                const int yb = y1 + hb[ph];
                int yl = y1 + hb[ph + 1] - 1;
                yl = yl > yb ? yl : yb;          // empty-bin guard
#pragma unroll
                for (int j = 0; j < 4; ++j) {
                    int y = yb + j;
                    y = y < yl ? y : yl;         // clamp: dupes same-bin
                    v[ph][j] = plane[y * W + lane];  // coalesced 256B
                }
            }
#pragma unroll
            for (int ph = 0; ph < OUT_H; ++ph)
                racc[ph] = fmaxf(fmaxf(v[ph][0], v[ph][1]),
                                 fmaxf(v[ph][2], v[ph][3]));
        }
        // Exact tall-bin batches: only bins with h>4 need rows yb+4..yb+6
        // (h <= ceil(48/7) = 7 -> at most 3 extra rows). Wave-uniform branch.
#pragma unroll
        for (int ph = 0; ph < OUT_H; ++ph) {
            const int h = hb[ph + 1] - hb[ph];
            if (h > 4) {                         // uniform per wave
                const int yb = y1 + hb[ph];
                const int yl = y1 + hb[ph + 1] - 1;
                float w0, w1, w2;
                {
                    int y0 = yb + 4;             int ya = y0 < yl ? y0 : yl;
                    int y1b = yb + 5;            int ybv = y1b < yl ? y1b : yl;
                    int y2b = yb + 6;            int ycv = y2b < yl ? y2b : yl;
                    w0 = plane[ya * W + lane];
                    w1 = plane[ybv * W + lane];
                    w2 = plane[ycv * W + lane];
                }
                racc[ph] = fmaxf(racc[ph], fmaxf(w0, fmaxf(w1, w2)));
            }
        }

        // Wave-private LDS round-trip (same-wave ordering: no barrier).
#pragma unroll
        for (int ph = 0; ph < OUT_H; ++ph) racc_lds[wave][ph][lane] = racc[ph];

        if (lane < NBINS) {
            const int ph = lane / OUT_W;
            const int pw = lane - ph * OUT_W;

            const int hsL = (ph * roi_h) / OUT_H;
            const int heL = ((ph + 1) * roi_h) / OUT_H;
            const int ws  = (pw * roi_w) / OUT_W;
            const int we  = ((pw + 1) * roi_w) / OUT_W;

            const int xs = x1 + ws;
            int xl = x1 + we - 1;
            xl = xl > xs ? xl : xs;

            float g[8];
#pragma unroll
            for (int j = 0; j < 8; ++j) {
                int x = xs + j;
                x = x < xl ? x : xl;
                g[j] = racc_lds[wave][ph][x];
            }
            float m = fmaxf(fmaxf(fmaxf(g[0], g[1]), fmaxf(g[2], g[3])),
                            fmaxf(fmaxf(g[4], g[5]), fmaxf(g[6], g[7])));

            const bool valid = (heL > hsL) && (we > ws);
            out[((size_t)(n * C + c)) * NBINS + lane] = valid ? m : 0.0f;
        }
        // no barrier needed between reps: racc_lds slice is wave-private,
        // same-wave LDS ordering guarantees read-after-write.
    }
}

extern "C" void kernel_launch(void* const* d_in, const int* in_sizes, int n_in,
                              void* d_out, int out_size, void* d_ws, size_t ws_size,
                              hipStream_t stream) {
    const float* feat = (const float*)d_in[0];
    const int*   rois = (const int*)d_in[1];
    float*       out  = (float*)d_out;

    const int N = in_sizes[1] / 5;     // 128 rois
    const int n_blocks = N * 64;       // 4 waves/block, 1 wave per (n,c)

    roipool_v11<<<n_blocks, 256, 0, stream>>>(feat, rois, out);
}

// Round 12
// 78.987 us; speedup vs baseline: 1.3261x; 1.3261x over previous
//
#include <hip/hip_runtime.h>
#include <math.h>

#define OUT_H 7
#define OUT_W 7
#define NBINS 49

// R11 counters: VALUBusy 60%, HBM 7%, conflicts 6% -> VALU-issue bound, and
// most VALU is per-roi overhead replicated per channel. v12: ONE WAVE = 4
// CHANNELS of one roi. Load address off=y*W+lane is channel-independent
// (computed once, 4 saddr-form loads share it); hb[]/clamps/phase-2 bounds
// computed once per wave instead of 4x. Total VALU insts ~9M -> ~3.8M.
// All memory ops statically unrolled with index clamping (dupes harmless
// under max); one vmcnt exposure per ph batch; wave-private LDS, no barriers.
// Bin bounds: exact integer floor(k*roi/7) == (k*roi)/7 (absmax 0 since R4).
// Grid bx = n*16+cgb: XCD = cgb%8 -> fixed 2MB feature subset per XCD (L2).
__global__ __launch_bounds__(256) void roipool_v12(
    const float* __restrict__ feat, const int* __restrict__ rois,
    float* __restrict__ out)
{
    constexpr int C = 256, H = 64, W = 64, HW = 64 * 64;
    __shared__ float racc_lds[4][4][OUT_H][65];   // [wave][ch][ph][x], pad 65

    const int bx   = blockIdx.x;
    const int n    = bx >> 4;              // roi (128)
    const int cgb  = bx & 15;              // channel block (16 ch)
    const int tid  = threadIdx.x;
    const int lane = tid & 63;             // == x
    const int wave = tid >> 6;
    const int c0   = cgb * 16 + wave * 4;  // this wave's 4 channels

    const int* r = rois + n * 5;
    const int b  = r[0];
    const int x1 = r[1];
    const int y1 = r[2];
    const int roi_w = r[3] - x1 + 1;
    const int roi_h = r[4] - y1 + 1;

    const float* p0 = feat + ((size_t)(b * C + c0)) * HW;  // ch k: p0 + k*HW

    int hb[OUT_H + 1];                     // statically indexed -> registers
#pragma unroll
    for (int k = 0; k <= OUT_H; ++k) hb[k] = (k * roi_h) / OUT_H;

    float racc[4][OUT_H];
#pragma unroll
    for (int ph = 0; ph < OUT_H; ++ph) {
        const int yb = y1 + hb[ph];
        int yl = y1 + hb[ph + 1] - 1;      // last row of bin
        yl = yl > yb ? yl : yb;            // empty-bin guard (stays in-image)
        float v[4][4];
#pragma unroll
        for (int j = 0; j < 4; ++j) {
            int y = yb + j;
            y = y < yl ? y : yl;           // clamp: duplicate rows, same bin
            const int off = y * W + lane;  // channel-independent address
#pragma unroll
            for (int ch = 0; ch < 4; ++ch)
                v[ch][j] = p0[ch * HW + off];   // coalesced 256B each
        }
#pragma unroll
        for (int ch = 0; ch < 4; ++ch)
            racc[ch][ph] = fmaxf(fmaxf(v[ch][0], v[ch][1]),
                                 fmaxf(v[ch][2], v[ch][3]));
    }
    // Tall bins (h>4; h <= ceil(48/7) = 7): 3 extra rows, uniform branch.
#pragma unroll
    for (int ph = 0; ph < OUT_H; ++ph) {
        const int h = hb[ph + 1] - hb[ph];
        if (h > 4) {
            const int yb = y1 + hb[ph];
            const int yl = y1 + hb[ph + 1] - 1;
            float v[4][3];
#pragma unroll
            for (int j = 0; j < 3; ++j) {
                int y = yb + 4 + j;
                y = y < yl ? y : yl;
                const int off = y * W + lane;
#pragma unroll
                for (int ch = 0; ch < 4; ++ch)
                    v[ch][j] = p0[ch * HW + off];
            }
#pragma unroll
            for (int ch = 0; ch < 4; ++ch)
                racc[ch][ph] = fmaxf(racc[ch][ph],
                                     fmaxf(v[ch][0], fmaxf(v[ch][1], v[ch][2])));
        }
    }

    // Wave-private LDS round-trip (same-wave ordering: no barrier needed).
#pragma unroll
    for (int ch = 0; ch < 4; ++ch)
#pragma unroll
        for (int ph = 0; ph < OUT_H; ++ph)
            racc_lds[wave][ch][ph][lane] = racc[ch][ph];

    if (lane < NBINS) {
        const int ph = lane / OUT_W;
        const int pw = lane - ph * OUT_W;

        const int hsL = (ph * roi_h) / OUT_H;   // bounds computed ONCE
        const int heL = ((ph + 1) * roi_h) / OUT_H;
        const int ws  = (pw * roi_w) / OUT_W;
        const int we  = ((pw + 1) * roi_w) / OUT_W;

        const int xs = x1 + ws;
        int xl = x1 + we - 1;
        xl = xl > xs ? xl : xs;                 // empty-bin guard
        const bool valid = (heL > hsL) && (we > ws);

        const float* base = &racc_lds[wave][0][ph][0];
#pragma unroll
        for (int ch = 0; ch < 4; ++ch) {        // extra ch: same vaddr + imm
            float g[8];                         // max bin width 7 <= 8
#pragma unroll
            for (int j = 0; j < 8; ++j) {
                int x = xs + j;
                x = x < xl ? x : xl;            // clamp: duplicates harmless
                g[j] = base[ch * (OUT_H * 65) + x];
            }
            float m = fmaxf(fmaxf(fmaxf(g[0], g[1]), fmaxf(g[2], g[3])),
                            fmaxf(fmaxf(g[4], g[5]), fmaxf(g[6], g[7])));
            // out[n][c0+ch][ph][pw]: 49 contiguous floats per store
            out[((size_t)(n * C + c0 + ch)) * NBINS + lane] = valid ? m : 0.0f;
        }
    }
}

extern "C" void kernel_launch(void* const* d_in, const int* in_sizes, int n_in,
                              void* d_out, int out_size, void* d_ws, size_t ws_size,
                              hipStream_t stream) {
    const float* feat = (const float*)d_in[0];
    const int*   rois = (const int*)d_in[1];
    float*       out  = (float*)d_out;

    const int N = in_sizes[1] / 5;     // 128 rois
    const int n_blocks = N * 16;       // 4 waves/block x 4 ch/wave = 16 ch
    roipool_v12<<<n_blocks, 256, 0, stream>>>(feat, rois, out);
}

// Round 13
// 75.956 us; speedup vs baseline: 1.3790x; 1.0399x over previous
//
#include <hip/hip_runtime.h>
#include <math.h>

#define OUT_H 7
#define OUT_W 7
#define NBINS 49
#define RFL(x) __builtin_amdgcn_readfirstlane(x)

// R11 counters: warm body is issue-bound, VALUBusy 60%, ~389 VALU/wave; ~60%
// of that is per-load 64-bit address + clamp math that is WAVE-UNIFORM (only
// `lane` is divergent). v13 forces all of it scalar via readfirstlane: row
// offsets/clamps/bases become SALU (issues in parallel with VALU), loads
// become saddr-form sharing one vaddr=lane*4. Keeps R10's occupancy shape
// (8192x256 blocks, 1 ch/wave, 32 waves/CU) because R12 proved that cutting
// waves 4x forfeits latency hiding. All accesses statically unrolled with
// scalar index clamping (dup rows harmless under max). Bin bounds: exact
// integer floor(k*roi/7) == (k*roi)/7 (absmax 0 since R4).
// Grid bx = n*64+cg: XCD = cg%8 -> fixed 2MB channel subset per XCD L2.
__global__ __launch_bounds__(256) void roipool_v13(
    const float* __restrict__ feat, const int* __restrict__ rois,
    float* __restrict__ out)
{
    constexpr int C = 256, H = 64, W = 64, HW = H * W;
    __shared__ float racc_lds[4][OUT_H][65];   // per-wave slice, +1 pad

    const int bx   = blockIdx.x;
    const int n    = bx >> 6;              // roi (128)
    const int cg   = bx & 63;              // channel group
    const int tid  = threadIdx.x;
    const int lane = tid & 63;             // == x
    const int wave = RFL(tid >> 6);        // force SGPR (uniform per wave)
    const int c    = cg * 4 + wave;        // scalar

    const int* r = rois + n * 5;
    const int b  = RFL(r[0]);
    const int x1 = RFL(r[1]);
    const int y1 = RFL(r[2]);
    const int roi_w = RFL(r[3]) - x1 + 1;  // scalar
    const int roi_h = RFL(r[4]) - y1 + 1;  // scalar

    const float* plane = feat + (size_t)(b * C + c) * HW;   // scalar base

    int hb[OUT_H + 1];                     // scalar bin bounds
#pragma unroll
    for (int k = 0; k <= OUT_H; ++k) hb[k] = RFL((k * roi_h) / OUT_H);

    float racc[OUT_H];
#pragma unroll
    for (int ph = 0; ph < OUT_H; ++ph) {
        const int rb = (y1 + hb[ph]) * W;            // scalar row offsets
        int rl = (y1 + hb[ph + 1] - 1) * W;          // last row of bin
        rl = rl > rb ? rl : rb;                      // empty-bin guard
        int r1 = rb + 1 * W; r1 = r1 < rl ? r1 : rl; // scalar clamps:
        int r2 = rb + 2 * W; r2 = r2 < rl ? r2 : rl; // dup rows same bin,
        int r3 = rb + 3 * W; r3 = r3 < rl ? r3 : rl; // harmless under max
        const float v0 = plane[rb + lane];           // saddr loads, shared
        const float v1 = plane[r1 + lane];           // vaddr = lane*4
        const float v2 = plane[r2 + lane];
        const float v3 = plane[r3 + lane];
        racc[ph] = fmaxf(fmaxf(v0, v1), fmaxf(v2, v3));
    }
    // Tall bins (h>4; h <= ceil(48/7)=7): 3 extra rows, scalar branch.
#pragma unroll
    for (int ph = 0; ph < OUT_H; ++ph) {
        const int h = hb[ph + 1] - hb[ph];           // scalar
        if (h > 4) {
            const int rb = (y1 + hb[ph]) * W;
            const int rl = (y1 + hb[ph + 1] - 1) * W;
            int r4 = rb + 4 * W; r4 = r4 < rl ? r4 : rl;
            int r5 = rb + 5 * W; r5 = r5 < rl ? r5 : rl;
            int r6 = rb + 6 * W; r6 = r6 < rl ? r6 : rl;
            const float v4 = plane[r4 + lane];
            const float v5 = plane[r5 + lane];
            const float v6 = plane[r6 + lane];
            racc[ph] = fmaxf(racc[ph], fmaxf(v4, fmaxf(v5, v6)));
        }
    }

    // Wave-private LDS round-trip (same-wave ordering: no barrier needed).
#pragma unroll
    for (int ph = 0; ph < OUT_H; ++ph) racc_lds[wave][ph][lane] = racc[ph];

    if (lane < NBINS) {
        const int ph = lane / OUT_W;          // per-lane (divergent) part
        const int pw = lane - ph * OUT_W;

        const int hsL = (ph * roi_h) / OUT_H;
        const int heL = ((ph + 1) * roi_h) / OUT_H;
        const int ws  = (pw * roi_w) / OUT_W;
        const int we  = ((pw + 1) * roi_w) / OUT_W;

        const int xs = x1 + ws;
        int xl = x1 + we - 1;
        xl = xl > xs ? xl : xs;               // empty-bin guard

        float g[8];                           // max bin width 7 <= 8
#pragma unroll
        for (int j = 0; j < 8; ++j) {
            int x = xs + j;
            x = x < xl ? x : xl;              // clamp: duplicates harmless
            g[j] = racc_lds[wave][ph][x];
        }
        float m = fmaxf(fmaxf(fmaxf(g[0], g[1]), fmaxf(g[2], g[3])),
                        fmaxf(fmaxf(g[4], g[5]), fmaxf(g[6], g[7])));

        const bool valid = (heL > hsL) && (we > ws);
        // out[n][c][ph][pw]: 49 contiguous floats, scalar base + lane
        out[(size_t)(n * C + c) * NBINS + lane] = valid ? m : 0.0f;
    }
}

extern "C" void kernel_launch(void* const* d_in, const int* in_sizes, int n_in,
                              void* d_out, int out_size, void* d_ws, size_t ws_size,
                              hipStream_t stream) {
    const float* feat = (const float*)d_in[0];
    const int*   rois = (const int*)d_in[1];
    float*       out  = (float*)d_out;

    const int N = in_sizes[1] / 5;     // 128 rois
    const int n_blocks = N * 64;       // 4 waves/block, 1 wave per (n,c)

    roipool_v13<<<n_blocks, 256, 0, stream>>>(feat, rois, out);
}